// Round 13
// baseline (472.005 us; speedup 1.0000x reference)
//
#include <hip/hip_runtime.h>
#include <cstdint>

#define DEV static __device__ __forceinline__

typedef __attribute__((ext_vector_type(8))) short short8v;     // 8 x bf16 bits
typedef __attribute__((ext_vector_type(4))) float f32x4;
typedef __attribute__((ext_vector_type(4))) float fl4;
typedef __attribute__((ext_vector_type(4))) unsigned short us4;
typedef __attribute__((ext_vector_type(8))) unsigned short us8;

DEV float b2f(unsigned short u) {
  union { unsigned int i; float f; } c; c.i = ((unsigned int)u) << 16; return c.f;
}
DEV unsigned short f2b(float f) {   // RNE float -> bf16 bits
  union { float f; unsigned int i; } c; c.f = f;
  unsigned int u = c.i;
  u += 0x7fffu + ((u >> 16) & 1u);
  return (unsigned short)(u >> 16);
}

DEV void gload16(const void* g, void* l) {  // async global->LDS, 16B/lane
  __builtin_amdgcn_global_load_lds(
      (const __attribute__((address_space(1))) unsigned int*)g,
      (__attribute__((address_space(3))) unsigned int*)l, 16, 0, 0);
}

DEV float red16(float v) {  // reduce across 16 lanes sharing lk (xor low 4 bits)
  v += __shfl_xor(v, 1); v += __shfl_xor(v, 2);
  v += __shfl_xor(v, 4); v += __shfl_xor(v, 8);
  return v;
}
DEV float red4lk(float v) { // reduce across the 4 lk groups (xor bits 4,5)
  v += __shfl_xor(v, 16); v += __shfl_xor(v, 32);
  return v;
}

// ---------------- elementwise f32 -> bf16 ----------------
__global__ __launch_bounds__(256) void k_f32_to_bf16(const float* __restrict__ src,
                                                     unsigned short* __restrict__ dst, long n) {
  long i = ((long)blockIdx.x * 256 + threadIdx.x) * 4;
  if (i >= n) return;
  fl4 v = *(const fl4*)(src + i);
  us4 o;
  o[0] = f2b(v[0]); o[1] = f2b(v[1]); o[2] = f2b(v[2]); o[3] = f2b(v[3]);
  *(us4*)(dst + i) = o;
}

// ---------------- concat biases into 3072-float buffer ----------------
__global__ __launch_bounds__(256) void k_bias_cat(const float* __restrict__ bq,
                                                  const float* __restrict__ bk,
                                                  const float* __restrict__ bv,
                                                  float* __restrict__ o) {
  const int t = blockIdx.x * 256 + threadIdx.x;   // 3072
  o[t] = t < 1024 ? bq[t] : (t < 2048 ? bk[t - 1024] : bv[t - 2048]);
}

// ---------------- finalize inverse norms ----------------
__global__ __launch_bounds__(256) void k_norms_fin(const float* __restrict__ pq,
                                                   const float* __restrict__ pk,
                                                   float* __restrict__ invq, float* __restrict__ invk) {
  const int gid = blockIdx.x * 256 + threadIdx.x;   // 16384
  invq[gid] = rsqrtf(pq[gid]);
  invk[gid] = rsqrtf(pk[gid]);
}

// ---------------- finalize tailor: 1/(L + rowsum(S) + eps*invq*colsum(Q)) ----------------
__global__ __launch_bounds__(256) void k_tailor_fin(const float* __restrict__ Srow,
                                                    const float* __restrict__ invq,
                                                    const float* __restrict__ qsum,
                                                    float* __restrict__ tailor) {
  const int gid = blockIdx.x * 256 + threadIdx.x;   // 16384
  tailor[gid] = 1.0f / (1024.0f + Srow[gid] + 1e-6f * invq[gid] * qsum[gid]);
}

#define MFMA_BF16 __builtin_amdgcn_mfma_f32_16x16x32_bf16
#define SBAR   __builtin_amdgcn_s_barrier()

// ---------------- 256x256 NT GEMM, BK=32, 16 waves (4Mx4N, 64x64 each), free-run ------
// OCCUPANCY round: per-thread regs halved (acc 4x4 f32x4 = 64; frags 32) and capped via
// __launch_bounds__(1024,4) -> 4 waves/SIMD (was 2 at ~228 regs). Same 256^2 tile, same
// free-run loop (4 LDS K-tile buffers, stage t+2, counted vmcnt(2), barrier per tile —
// own-vmcnt drains own stage(t) BEFORE the barrier, so tile t is globally visible).
// 1024 threads = one full 16-KB A or B buffer per gload16 -> STAGE = 2 loads.
// LDS chunk-swizzle (verified 0-conflict) + XCD-bijective block swizzle carried over.
// Epilogues: LDS-roundtrip (verified R11/R12), indices re-derived for 16-wave geometry.
// EPI 1: final fused fp32 epilogue.  EPI 4: scaled-S + row sums.  EPI 5: merged QKV.
template<int EPI>
__global__ __launch_bounds__(1024, 4)
void k_g256(const unsigned short* __restrict__ A,
            const unsigned short* __restrict__ Bt,
            void* __restrict__ O0, void* __restrict__ O1, void* __restrict__ O2,
            int K, long sA, long sB, long sC,
            const float* __restrict__ bias,
            float* __restrict__ r1, float* __restrict__ r2,
            float* __restrict__ r3, float* __restrict__ r4,
            const unsigned short* __restrict__ xh,
            const float* __restrict__ Vsum,
            const float* __restrict__ tailor,
            const float* __restrict__ gptr) {
  __shared__ __align__(16) unsigned short LDSU[65536];   // 128 KiB: 4 K-tile bufs, then scratch

  const int tid = threadIdx.x;
  const int wv = tid >> 6, lane = tid & 63;
  const int wr = wv >> 2, wcn = wv & 3;          // 4 x 4 wave grid, 64x64 each
  const int l15 = lane & 15, lk = lane >> 4;

  // XCD-bijective swizzle over (x,y); nwg % 8 == 0 for all grids used
  const int nx = gridDim.x;
  const int nwg = nx * gridDim.y;
  const int lin = blockIdx.y * nx + blockIdx.x;
  const int cpx = nwg >> 3;
  const int wg = (lin & 7) * cpx + (lin >> 3);
  const int bn = wg % nx;
  const int bm = wg / nx;
  const int bz = blockIdx.z;

  const unsigned short* Ab = A + (long)bz * sA + (long)bm * 256 * K;
  const unsigned short* Bb = Bt + (long)bz * sB + (long)bn * 256 * K;

  // staging (BK=32): 1024 threads cover a full 256x32 buffer: row = tid>>2,
  // physical chunk tid&3, pre-swizzled global chunk = (tid&3) ^ ((row>>1)&3).
  const int scsw = (tid & 3) ^ ((tid >> 3) & 3);
  const long gOff = (long)(tid >> 2) * K + (long)scsw * 8;   // + t*32
  const int ldsb = wv * 512;

  // read-side swizzle: chunk' = lk ^ ((row>>1)&3); row bits 1-2 come from l15 only.
  const int rdsw = (lk ^ ((l15 >> 1) & 3)) * 8;
  const int abase = (wr * 64 + l15) * 32;    // + i*512
  const int bbase = (wcn * 64 + l15) * 32;   // + j*512

  f32x4 acc[4][4];
#pragma unroll
  for (int i = 0; i < 4; ++i)
#pragma unroll
    for (int j = 0; j < 4; ++j) acc[i][j] = (f32x4){0.f, 0.f, 0.f, 0.f};

#define STAGE(T, BUF)                                                        \
  {                                                                          \
    const long kb = (long)(T) * 32;                                          \
    gload16(Ab + kb + gOff, LDSU + (BUF) * 8192 + ldsb);                     \
    gload16(Bb + kb + gOff, LDSU + 32768 + (BUF) * 8192 + ldsb);             \
  }

  // prologue: stage tiles 0,1 into buffers 0,1
  STAGE(0, 0)
  STAGE(1, 1)

  const int NT = K >> 5;
  for (int t = 0; t < NT; ++t) {
    if (t < NT - 1) { asm volatile("s_waitcnt vmcnt(2)" ::: "memory"); }  // own stage(t) landed
    else            { asm volatile("s_waitcnt vmcnt(0)" ::: "memory"); }
    SBAR;                                        // all waves' stage(t) landed -> tile t visible
    if (t + 2 < NT) STAGE(t + 2, (t + 2) & 3)

    const unsigned short* Asc = LDSU + (t & 3) * 8192;
    const unsigned short* Bsc = LDSU + 32768 + (t & 3) * 8192;
    short8v Bf[4], Af[4];
#pragma unroll
    for (int j = 0; j < 4; ++j)
      Bf[j] = *(const short8v*)&Bsc[bbase + j * 512 + rdsw];
#pragma unroll
    for (int i = 0; i < 4; ++i)
      Af[i] = *(const short8v*)&Asc[abase + i * 512 + rdsw];

    __builtin_amdgcn_s_setprio(1);
#pragma unroll
    for (int i = 0; i < 4; ++i)
#pragma unroll
      for (int j = 0; j < 4; ++j)
        acc[i][j] = MFMA_BF16(Af[i], Bf[j], acc[i][j], 0, 0, 0);
    __builtin_amdgcn_s_setprio(0);
  }
#undef STAGE
  SBAR;   // all waves done with K-loop LDS -> safe to reuse as epilogue scratch

  const int row0 = bm * 256 + wr * 64;
  const int col0 = bn * 256 + wcn * 64;
  unsigned short* sc = LDSU;       // [256 rows][256 cols] bf16, cell-swizzled
  float* scf = (float*)LDSU;       // [128 rows][256 cols] fp32, cell-swizzled

  if constexpr (EPI == 1) {
    float* Cb = (float*)O0 + (long)bz * sC;
    const float g = gptr[0];
#pragma unroll
    for (int h = 0; h < 2; ++h) {
      if ((wr >> 1) == h) {
#pragma unroll
        for (int i = 0; i < 4; ++i)
#pragma unroll
          for (int j = 0; j < 4; ++j) {
            const int col = wcn * 64 + j * 16 + l15;
            const int cc = col >> 2, c3 = col & 3;
#pragma unroll
            for (int r = 0; r < 4; ++r) {
              const int rl = (wr & 1) * 64 + i * 16 + lk * 4 + r;   // [0,128)
              scf[rl * 256 + ((cc ^ (rl & 15)) << 2) + c3] = acc[i][j][r];
            }
          }
      }
      SBAR;
#pragma unroll
      for (int it = 0; it < 8; ++it) {
        const int rl = it * 16 + wv;                   // [0,128)
        const int rg = bm * 256 + h * 128 + rl;        // [0,2048)
        const int c = lane;                            // f32 cell [0,64)
        fl4 a4 = *(const fl4*)&scf[rl * 256 + ((c ^ (rl & 15)) << 2)];
        const int cg = bn * 256 + c * 4;
        us4 xv = *(const us4*)&xh[((long)bz * 2048 + rg) * 1024 + cg];
        fl4 tl = *(const fl4*)&tailor[bz * 1024 + cg];
        const float vs = Vsum[bz * 2048 + rg];
        fl4 o;
#pragma unroll
        for (int q = 0; q < 4; ++q) o[q] = b2f(xv[q]) + g * ((vs + a4[q]) * tl[q]);
        *(fl4*)&Cb[(long)rg * 1024 + cg] = o;
      }
      if (h == 0) SBAR;
    }
  } else if constexpr (EPI == 4) {
    // S[p][l] = invq[p]*invk[l]*acc; Srow[p] += scaled row sum; roundtrip -> us8 stores
    unsigned short* Cb = (unsigned short*)O0 + (long)bz * sC;
    float ivk[4];
#pragma unroll
    for (int j = 0; j < 4; ++j) ivk[j] = r3[bz * 1024 + col0 + j * 16 + l15];
#pragma unroll
    for (int i = 0; i < 4; ++i) {
      float ivq[4];
#pragma unroll
      for (int r = 0; r < 4; ++r) ivq[r] = r2[bz * 1024 + row0 + i * 16 + lk * 4 + r];
#pragma unroll
      for (int r = 0; r < 4; ++r) {
        const int rl = wr * 64 + i * 16 + lk * 4 + r;   // [0,256)
        float sm = 0.f;
#pragma unroll
        for (int j = 0; j < 4; ++j) {
          const float v = acc[i][j][r] * ivq[r] * ivk[j];
          sm += v;
          const int col = wcn * 64 + j * 16 + l15;
          sc[rl * 256 + (((col >> 3) ^ (rl & 15)) << 3) + (col & 7)] = f2b(v);
        }
        sm = red16(sm);
        if (l15 == 0) atomicAdd(&r1[(long)bz * 1024 + row0 + i * 16 + lk * 4 + r], sm);
      }
    }
    SBAR;
#pragma unroll
    for (int it = 0; it < 8; ++it) {
      const int rl = it * 32 + (tid >> 5);              // [0,256)
      const int c = lane & 31;
      us8 v = *(const us8*)&sc[rl * 256 + ((c ^ (rl & 15)) << 3)];
      *(us8*)&Cb[(long)(bm * 256 + rl) * 1024 + bn * 256 + c * 8] = v;
    }
  } else {  // EPI == 5: merged QKV
    const int seg = bn >> 2;             // 0=Q, 1=K, 2=V
    const int b = bm >> 3;               // batch
    float bvj[4];
#pragma unroll
    for (int j = 0; j < 4; ++j) bvj[j] = bias[col0 + j * 16 + l15];
    const int colL0 = col0 & 1023;
    if (seg < 2) {
      // stage transposed: p = local col [0,256), m = local row [0,256)
#pragma unroll
      for (int i = 0; i < 4; ++i)
#pragma unroll
        for (int j = 0; j < 4; ++j) {
          const int p = wcn * 64 + j * 16 + l15;
          const int m = wr * 64 + i * 16 + lk * 4;     // aligned 4
          us4 o;
#pragma unroll
          for (int r = 0; r < 4; ++r) o[r] = f2b(acc[i][j][r] + bvj[j]);
          *(us4*)&sc[p * 256 + (((m >> 3) ^ (p & 15)) << 3) + (m & 7)] = o;
        }
      // col reductions (pre-stage values, in-register)
#pragma unroll
      for (int j = 0; j < 4; ++j) {
        const int colL = colL0 + j * 16 + l15;
        float ss = 0.f, sm = 0.f;
#pragma unroll
        for (int i = 0; i < 4; ++i)
#pragma unroll
          for (int r = 0; r < 4; ++r) {
            const float v = acc[i][j][r] + bvj[j];
            ss += v * v; sm += v;
          }
        ss = red4lk(ss);
        if (seg == 0) sm = red4lk(sm);
        if (lk == 0) {
          atomicAdd(&(seg == 0 ? r1 : r3)[(long)b * 1024 + colL], ss);
          if (seg == 0) atomicAdd(&r2[(long)b * 1024 + colL], sm);
        }
      }
      SBAR;
      unsigned short* tp = (seg == 0 ? (unsigned short*)O0 : (unsigned short*)O1)
                           + (long)b * 2097152;        // 1024*2048 per batch
      const int P0 = (bn & 3) * 256;
      const int M0 = (bm & 7) * 256;
#pragma unroll
      for (int it = 0; it < 8; ++it) {
        const int p = it * 32 + (tid >> 5);            // [0,256)
        const int c = lane & 31;
        us8 v = *(const us8*)&sc[p * 256 + ((c ^ (p & 15)) << 3)];
        *(us8*)&tp[(long)(P0 + p) * 2048 + M0 + c * 8] = v;
      }
    } else {
      // V: stage normal layout + row sums
#pragma unroll
      for (int i = 0; i < 4; ++i)
#pragma unroll
        for (int r = 0; r < 4; ++r) {
          const int rl = wr * 64 + i * 16 + lk * 4 + r;   // [0,256)
          float sm = 0.f;
#pragma unroll
          for (int j = 0; j < 4; ++j) {
            const float v = acc[i][j][r] + bvj[j];
            sm += v;
            const int col = wcn * 64 + j * 16 + l15;
            sc[rl * 256 + (((col >> 3) ^ (rl & 15)) << 3) + (col & 7)] = f2b(v);
          }
          sm = red16(sm);
          if (l15 == 0) atomicAdd(&r4[row0 + i * 16 + lk * 4 + r], sm);
        }
      SBAR;
      unsigned short* outp = (unsigned short*)O2;
      const int C0 = (bn & 3) * 256;
#pragma unroll
      for (int it = 0; it < 8; ++it) {
        const int rl = it * 32 + (tid >> 5);
        const int c = lane & 31;
        us8 v = *(const us8*)&sc[rl * 256 + ((c ^ (rl & 15)) << 3)];
        *(us8*)&outp[(long)(bm * 256 + rl) * 1024 + C0 + c * 8] = v;
      }
    }
  }
}

extern "C" void kernel_launch(void* const* d_in, const int* in_sizes, int n_in,
                              void* d_out, int out_size, void* d_ws, size_t ws_size,
                              hipStream_t stream) {
  (void)in_sizes; (void)n_in; (void)out_size;
  const float* x     = (const float*)d_in[0];
  const float* Wq    = (const float*)d_in[1];
  const float* bq    = (const float*)d_in[2];
  const float* Wk    = (const float*)d_in[3];
  const float* bk    = (const float*)d_in[4];
  const float* Wv    = (const float*)d_in[5];
  const float* bv    = (const float*)d_in[6];
  const float* gamma = (const float*)d_in[7];

  // B=16, C=2048, L=D=1024
  const long NE = 16L * 2048 * 1024;
  const long BUF = NE * 2;                    // bytes per bf16 tensor

  char* w = (char*)d_ws;
  unsigned short* QT  = (unsigned short*)(w);            // [16][1024][2048] bf16
  unsigned short* KT  = (unsigned short*)(w + BUF);      // [16][1024][2048] bf16
  unsigned short* Vh  = (unsigned short*)(w + 2 * BUF);  // [32768][1024]
  unsigned short* xh  = (unsigned short*)(w + 3 * BUF);  // live to the end
  unsigned short* S   = (unsigned short*)(w + 4 * BUF);  // [16][1024][1024] (33.5 MB)
  size_t off = 4 * (size_t)BUF + (size_t)BUF / 2 + 4096;
  unsigned short* Wqkvh = (unsigned short*)(w + off); off += 3 * 2097152;  // Wq|Wk|Wv contiguous
  char* accbase = w + off;
  float* pq     = (float*)(w + off); off += 65536;       // col sumsq of Q  (16x1024)
  float* qsum   = (float*)(w + off); off += 65536;       // col sum of Q
  float* pk     = (float*)(w + off); off += 65536;       // col sumsq of K
  float* Vsum   = (float*)(w + off); off += 131072;      // row sum of V    (16x2048)
  float* Srow   = (float*)(w + off); off += 65536;       // row sum of scaled S (16x1024)
  const size_t accbytes = (size_t)(w + off - accbase);
  float* invq   = (float*)(w + off); off += 65536;
  float* invk   = (float*)(w + off); off += 65536;
  float* tailor = (float*)(w + off); off += 65536;
  float* bqkv   = (float*)(w + off); off += 12288;
  if (ws_size < off) return;

  // 0) zero atomic accumulators
  hipMemsetAsync(accbase, 0, accbytes, stream);

  // 1) casts + bias concat
  k_f32_to_bf16<<<dim3((unsigned)(NE / 1024)), 256, 0, stream>>>(x, xh, NE);
  k_f32_to_bf16<<<dim3(1024), 256, 0, stream>>>(Wq, Wqkvh, 1048576);
  k_f32_to_bf16<<<dim3(1024), 256, 0, stream>>>(Wk, Wqkvh + 1048576, 1048576);
  k_f32_to_bf16<<<dim3(1024), 256, 0, stream>>>(Wv, Wqkvh + 2097152, 1048576);
  k_bias_cat<<<dim3(12), 256, 0, stream>>>(bq, bk, bv, bqkv);

  // 2) merged QKV GEMM: M=32768, N=3072, K=1024; Q,K stored transposed + fused reductions
  k_g256<5><<<dim3(12, 128, 1), 1024, 0, stream>>>(
      xh, Wqkvh, QT, KT, Vh, 1024, 0, 0, 0, bqkv,
      pq, qsum, pk, Vsum, nullptr, nullptr, nullptr, nullptr);

  // 3) inverse norms
  k_norms_fin<<<dim3(64), 256, 0, stream>>>(pq, pk, invq, invk);

  // 4) S = invq.(QT x KT^T).invk per batch (M=N=1024, K=2048) + scaled row sums
  k_g256<4><<<dim3(4, 4, 16), 1024, 0, stream>>>(
      QT, KT, S, nullptr, nullptr, 2048, 1024L * 2048, 1024L * 2048, 1024L * 1024,
      nullptr, Srow, invq, invk, nullptr, nullptr, nullptr, nullptr, nullptr);

  // 5) tailor
  k_tailor_fin<<<dim3(64), 256, 0, stream>>>(Srow, invq, qsum, tailor);

  // 6) out = xh + gamma*(Vsum + V x S^T) * tailor   (M=2048/batch, N=1024, K=1024)
  k_g256<1><<<dim3(4, 8, 16), 1024, 0, stream>>>(
      Vh, S, d_out, nullptr, nullptr, 1024, 2048L * 1024, 1024L * 1024, 2048L * 1024,
      nullptr, nullptr, nullptr, nullptr, nullptr, xh, Vsum, tailor, gamma);
}